// Round 9
// baseline (281.783 us; speedup 1.0000x reference)
//
#include <hip/hip_runtime.h>
#include <stdint.h>

// Correlation cost volume, MAX_DISP=4 (81 displacements).
// out[b,(dy+4)*9+(dx+4),y,x] = (1/C) * sum_c first[b,c,y,x]*second[b,c,y+dy,x+dx]
//
// R16: UNIQUE-BYTES STAGING via global_load_lds. R15 post-mortem: phys-reg
// depth-4 pipeline worked (103.7us, no spill) but VALUBusy 28% and back-solved
// load latency ~7000cyc => VMEM QUEUEING, not latency: 4KB/wave-step requested
// (1.1KB unique; window chunks overlap 3x across lanes, first re-read 9x
// across dy-blocks) = 45us of pure TCP service per CU. Request volume is the
// binder -> stage UNIQUE bytes once per block into LDS and serve the 3x
// window broadcast from the LDS pipe (2-4x TCP bandwidth).
// Structure: dy-fused block (R11/R12) done right:
//  - 64x4 tile, 9 waves (wave w = dy), 4px/lane, float4 LDS reads.
//  - global_load_lds DMA: NO VGPR dest -> no R14 phi-copy hazard, no R15
//    phys-reg pinning. Depth-3, 4 buffers, counted vmcnt(2) (NEVER 0 in
//    loop), raw s_barrier (no vmcnt drain -- prefetch spans barriers; T3/T4).
//  - Staging map exact: (12+4) rows x 72 cols = 1152 floats = 288 lanes x
//    16B, dest = wave-uniform base + lane*16 (the DMA constraint, m104).
//    OOB lanes DMA from a BSS zero page with channel-stride 0 (R15-proven).
//  - Bank math: row stride 72 == 8 (mod 32) -> a wave's 4 rows hit disjoint
//    bank quarters; 16 lanes x 4 floats = 2-way (free, m136).
// Per-CU floors: TCP 1.7MB (was 6.9), LDS 15.6MB (~25-50us), VALU ~31us,
// HBM ~180MB (~29us). launch_bounds(576,5): cap 102 > ~90 live set.

#define B_    4
#define C_    128
#define H_    128
#define W_    192
#define HW_   (H_ * W_)
#define CHW_  (C_ * HW_)
#define CHB   ((uint64_t)HW_ * 4)   // channel stride in bytes

#define TX    64
#define TY    4
#define SROWS 12                    // TY + 8 second rows
#define FROWS 4                     // TY first rows
#define SCOLS 72                    // TX + 8
#define BUFFL ((SROWS + FROWS) * SCOLS)   // 1152 floats = 4608 B
#define NBUF  4

__device__ __align__(16) float ZPAGE[4];   // BSS: guaranteed zeros

typedef __attribute__((address_space(3))) void       lds_void_t;
typedef const __attribute__((address_space(1))) void glb_void_t;

#define WAITVM(N)                                                        \
    asm volatile("s_waitcnt vmcnt(" #N ")" ::: "memory");                \
    __builtin_amdgcn_sched_barrier(0);

#define BARRIER()                                                        \
    { __builtin_amdgcn_s_barrier(); asm volatile("" ::: "memory"); }

__global__ __launch_bounds__(576, 5)
void corr_kernel(const float* __restrict__ first,
                 const float* __restrict__ second,
                 float* __restrict__ out)
{
    __shared__ __align__(16) float lds[NBUF][BUFFL];

    const int t  = threadIdx.x;      // 0..575
    const int w  = t >> 6;           // wave = dyi (0..8)
    const int l  = t & 63;
    const int lx = l & 15;           // 16 lanes across x, 4 px each
    const int ly = l >> 4;           // 4 rows
    const int x0 = blockIdx.x * TX;
    const int y0 = blockIdx.y * TY;
    const int b  = blockIdx.z;

    // ---- staging map: thread t (t<288) DMAs float4 #t of the region ----
    // region float offset 4t: row r = t/18, col c4 = (t%18)*4.
    // r<12: second[b, c, y0-4+r, x0-4+c4 .. +3]; r>=12: first[b, c, y0+r-12,
    // x0+c4 .. +3] (c4<64; the 72-col first rows' tail cols are dummies).
    // 16B chunks never straddle validity (x0, W, col all mult of 4).
    const bool stager = (t < 288);
    uint64_t gq = (uint64_t)(uintptr_t)ZPAGE;
    uint64_t gs = 0;
    if (stager) {
        const int r  = t / 18;           // 0..15
        const int c4 = (t % 18) * 4;     // 0..68
        bool valid;
        const float* gp;
        if (r < SROWS) {
            const int yy = y0 - 4 + r;
            const int xx = x0 - 4 + c4;
            valid = (yy >= 0) && (yy < H_) && (xx >= 0) && (xx + 3 < W_);
            gp = second + (size_t)b * CHW_ + (size_t)yy * W_ + xx;
        } else {
            const int yy = y0 + (r - SROWS);
            const int xx = x0 + c4;
            valid = (c4 < TX);           // rows always in-range
            gp = first + (size_t)b * CHW_ + (size_t)yy * W_ + xx;
        }
        if (valid) { gq = (uint64_t)(uintptr_t)gp; gs = CHB; }
    }

// DMA one float4 per stager thread for channel CH into buffer BUF.
// dest = lds base + t*16: wave-uniform base (1024*w) + lane*16 -- exactly
// the global_load_lds layout constraint.
#define STAGE(CH, BUF)                                                   \
    if (stager) {                                                        \
        __builtin_amdgcn_global_load_lds(                                \
            (glb_void_t*)(uintptr_t)(gq + (uint64_t)(CH) * gs),          \
            (lds_void_t*)((float*)lds + (size_t)(BUF) * BUFFL + 4 * t),  \
            16, 0, 0);                                                   \
    }

    float4 acc[9];
    #pragma unroll
    for (int i = 0; i < 9; ++i) acc[i] = make_float4(0.f, 0.f, 0.f, 0.f);

    // compute channel K from buf[K&3]: wave w reads second rows ly+w
    // (= y+dy), window cols 4lx..4lx+11; first row 12+ly, cols 4lx..+3.
#define COMPUTE(K)                                                       \
    {                                                                    \
        const float* bp = (const float*)lds + (size_t)((K) & 3) * BUFFL; \
        const float* rp = bp + (ly + w) * SCOLS + 4 * lx;                \
        float4 f  = *(const float4*)(bp + (SROWS + ly) * SCOLS + 4 * lx);\
        float4 w0 = *(const float4*)(rp);                                \
        float4 w1 = *(const float4*)(rp + 4);                            \
        float4 w2 = *(const float4*)(rp + 8);                            \
        float wv[12];                                                    \
        *(float4*)(wv + 0) = w0;                                         \
        *(float4*)(wv + 4) = w1;                                         \
        *(float4*)(wv + 8) = w2;                                         \
        _Pragma("unroll")                                                \
        for (int dxi = 0; dxi < 9; ++dxi) {                              \
            acc[dxi].x += f.x * wv[dxi + 0];                             \
            acc[dxi].y += f.y * wv[dxi + 1];                             \
            acc[dxi].z += f.z * wv[dxi + 2];                             \
            acc[dxi].w += f.w * wv[dxi + 3];                             \
        }                                                                \
    }

    // prologue: channels 0..2 in flight (depth-3)
    STAGE(0, 0)
    STAGE(1, 1)
    STAGE(2, 2)
    WAITVM(2)          // ch0 landed in LDS
    BARRIER()

    // steady state: compute ch k, stage ch k+3; buf[k&3] is free for ch k+4's
    // writer only after barrier k (reads done) -- 4 buffers, depth 3: safe.
    #pragma unroll 1
    for (int k = 0; k < 125; ++k) {
        STAGE(k + 3, (k + 3) & 3)
        COMPUTE(k)
        WAITVM(2)      // ch k+1 landed; k+2,k+3 stay in flight across barrier
        BARRIER()
    }
    // tail: drain 1/0
    COMPUTE(125)
    WAITVM(1)
    BARRIER()
    COMPUTE(126)
    WAITVM(0)
    BARRIER()
    COMPUTE(127)

    // epilogue: out[b, w*9 + dxi, y, X..X+3]
    const float scale = 1.0f / (float)C_;
    const int X = x0 + 4 * lx;
    const int y = y0 + ly;
    float* ob = out + ((size_t)b * 81 + (size_t)w * 9) * HW_
                    + (size_t)y * W_ + X;
    #pragma unroll
    for (int dxi = 0; dxi < 9; ++dxi) {
        float4 r4 = acc[dxi];
        r4.x *= scale; r4.y *= scale; r4.z *= scale; r4.w *= scale;
        *(float4*)(ob + (size_t)dxi * HW_) = r4;
    }
}

extern "C" void kernel_launch(void* const* d_in, const int* in_sizes, int n_in,
                              void* d_out, int out_size, void* d_ws, size_t ws_size,
                              hipStream_t stream) {
    const float* first  = (const float*)d_in[0];
    const float* second = (const float*)d_in[1];
    float* out = (float*)d_out;

    dim3 grid(W_ / TX, H_ / TY, B_);   // 3 x 32 x 4 = 384 blocks
    dim3 block(576);                   // 9 waves: one per dy
    corr_kernel<<<grid, block, 0, stream>>>(first, second, out);
}

// Round 10
// 183.746 us; speedup vs baseline: 1.5335x; 1.5335x over previous
//
#include <hip/hip_runtime.h>
#include <stdint.h>

// Correlation cost volume, MAX_DISP=4 (81 displacements).
// out[b,(dy+4)*9+(dx+4),y,x] = (1/C) * sum_c first[b,c,y,x]*second[b,c,y+dy,x+dx]
//
// R17 = R15 (phys-reg depth-4 pipeline, 103.7us) with 8 px/lane register
// reuse. R16 post-mortem: LDS broadcast delivers ~85 B/cyc vs TCP 64 B/cyc
// (only 1.3x) and cost grid starvation + per-channel barriers -> 187us. The
// remaining lever is REGISTER reuse: bytes/px-ch 16 -> 12 (window [X-4,X+12)
// = 4 float4 + first 2 float4 = 96B for 72 FMA), VMEM instrs/px 1.0 -> 0.75.
// Mechanics identical to R15 (the only structure that held):
//  - slots pinned v32..v127 (4 slots x [16 window + 8 first]), acc v128-199
//  - every loop asm clobbers v32-v199 -> no RA phi-copies into in-flight regs
//  - counted s_waitcnt vmcnt(18) steady (24 in flight, never 0), drain
//    18/12/6/0, sched_barrier(0) after each wait (rule #18)
//  - invalid chunks: zero-page pointer with stride 0 (no cndmask in loop)
//  - zero LDS, zero barriers, natural block mapping
// Wave = 8 lx (8 px) x 8 rows; block 128 thr = 2 waves -> 64x16 tile.
// Grid 3x8x36 = 864 blocks x 2 waves = 1728 waves = 6.75/CU; VGPR ~200 ->
// launch_bounds(128,2) cap 256, HW allows 8 waves/CU at <=256.

#define B_    4
#define C_    128
#define H_    128
#define W_    192
#define HW_   (H_ * W_)
#define CHW_  (C_ * HW_)
#define CHB   ((uint64_t)HW_ * 4)   // channel stride in bytes

#define TX    64
#define TY    16

__device__ __align__(32) float ZPAGE[8];   // BSS zeros (32B: base + offset:16)

#define PIPE_CLOB \
    "v32","v33","v34","v35","v36","v37","v38","v39","v40","v41","v42","v43", \
    "v44","v45","v46","v47","v48","v49","v50","v51","v52","v53","v54","v55", \
    "v56","v57","v58","v59","v60","v61","v62","v63","v64","v65","v66","v67", \
    "v68","v69","v70","v71","v72","v73","v74","v75","v76","v77","v78","v79", \
    "v80","v81","v82","v83","v84","v85","v86","v87","v88","v89","v90","v91", \
    "v92","v93","v94","v95","v96","v97","v98","v99","v100","v101","v102", \
    "v103","v104","v105","v106","v107","v108","v109","v110","v111","v112", \
    "v113","v114","v115","v116","v117","v118","v119","v120","v121","v122", \
    "v123","v124","v125","v126","v127","v128","v129","v130","v131","v132", \
    "v133","v134","v135","v136","v137","v138","v139","v140","v141","v142", \
    "v143","v144","v145","v146","v147","v148","v149","v150","v151","v152", \
    "v153","v154","v155","v156","v157","v158","v159","v160","v161","v162", \
    "v163","v164","v165","v166","v167","v168","v169","v170","v171","v172", \
    "v173","v174","v175","v176","v177","v178","v179","v180","v181","v182", \
    "v183","v184","v185","v186","v187","v188","v189","v190","v191","v192", \
    "v193","v194","v195","v196","v197","v198","v199"

#define FM(a,f,w) "v_fmac_f32 v" #a ", v" #f ", v" #w "\n\t"
#define ZM(n)     "v_mov_b32 v" #n ", 0\n\t"

// acc(dxi,p) = v(128+8*dxi+p) += f(F+p) * wv(W+dxi+p), p=0..7
// slot A: wv v32-47, f v48-55
#define FMA_A asm volatile( \
    FM(128,48,32) FM(129,49,33) FM(130,50,34) FM(131,51,35) FM(132,52,36) FM(133,53,37) FM(134,54,38) FM(135,55,39) \
    FM(136,48,33) FM(137,49,34) FM(138,50,35) FM(139,51,36) FM(140,52,37) FM(141,53,38) FM(142,54,39) FM(143,55,40) \
    FM(144,48,34) FM(145,49,35) FM(146,50,36) FM(147,51,37) FM(148,52,38) FM(149,53,39) FM(150,54,40) FM(151,55,41) \
    FM(152,48,35) FM(153,49,36) FM(154,50,37) FM(155,51,38) FM(156,52,39) FM(157,53,40) FM(158,54,41) FM(159,55,42) \
    FM(160,48,36) FM(161,49,37) FM(162,50,38) FM(163,51,39) FM(164,52,40) FM(165,53,41) FM(166,54,42) FM(167,55,43) \
    FM(168,48,37) FM(169,49,38) FM(170,50,39) FM(171,51,40) FM(172,52,41) FM(173,53,42) FM(174,54,43) FM(175,55,44) \
    FM(176,48,38) FM(177,49,39) FM(178,50,40) FM(179,51,41) FM(180,52,42) FM(181,53,43) FM(182,54,44) FM(183,55,45) \
    FM(184,48,39) FM(185,49,40) FM(186,50,41) FM(187,51,42) FM(188,52,43) FM(189,53,44) FM(190,54,45) FM(191,55,46) \
    FM(192,48,40) FM(193,49,41) FM(194,50,42) FM(195,51,43) FM(196,52,44) FM(197,53,45) FM(198,54,46) FM(199,55,47) \
    ::: PIPE_CLOB)

// slot B: wv v56-71, f v72-79
#define FMA_B asm volatile( \
    FM(128,72,56) FM(129,73,57) FM(130,74,58) FM(131,75,59) FM(132,76,60) FM(133,77,61) FM(134,78,62) FM(135,79,63) \
    FM(136,72,57) FM(137,73,58) FM(138,74,59) FM(139,75,60) FM(140,76,61) FM(141,77,62) FM(142,78,63) FM(143,79,64) \
    FM(144,72,58) FM(145,73,59) FM(146,74,60) FM(147,75,61) FM(148,76,62) FM(149,77,63) FM(150,78,64) FM(151,79,65) \
    FM(152,72,59) FM(153,73,60) FM(154,74,61) FM(155,75,62) FM(156,76,63) FM(157,77,64) FM(158,78,65) FM(159,79,66) \
    FM(160,72,60) FM(161,73,61) FM(162,74,62) FM(163,75,63) FM(164,76,64) FM(165,77,65) FM(166,78,66) FM(167,79,67) \
    FM(168,72,61) FM(169,73,62) FM(170,74,63) FM(171,75,64) FM(172,76,65) FM(173,77,66) FM(174,78,67) FM(175,79,68) \
    FM(176,72,62) FM(177,73,63) FM(178,74,64) FM(179,75,65) FM(180,76,66) FM(181,77,67) FM(182,78,68) FM(183,79,69) \
    FM(184,72,63) FM(185,73,64) FM(186,74,65) FM(187,75,66) FM(188,76,67) FM(189,77,68) FM(190,78,69) FM(191,79,70) \
    FM(192,72,64) FM(193,73,65) FM(194,74,66) FM(195,75,67) FM(196,76,68) FM(197,77,69) FM(198,78,70) FM(199,79,71) \
    ::: PIPE_CLOB)

// slot C: wv v80-95, f v96-103
#define FMA_C asm volatile( \
    FM(128,96,80) FM(129,97,81) FM(130,98,82) FM(131,99,83) FM(132,100,84) FM(133,101,85) FM(134,102,86) FM(135,103,87) \
    FM(136,96,81) FM(137,97,82) FM(138,98,83) FM(139,99,84) FM(140,100,85) FM(141,101,86) FM(142,102,87) FM(143,103,88) \
    FM(144,96,82) FM(145,97,83) FM(146,98,84) FM(147,99,85) FM(148,100,86) FM(149,101,87) FM(150,102,88) FM(151,103,89) \
    FM(152,96,83) FM(153,97,84) FM(154,98,85) FM(155,99,86) FM(156,100,87) FM(157,101,88) FM(158,102,89) FM(159,103,90) \
    FM(160,96,84) FM(161,97,85) FM(162,98,86) FM(163,99,87) FM(164,100,88) FM(165,101,89) FM(166,102,90) FM(167,103,91) \
    FM(168,96,85) FM(169,97,86) FM(170,98,87) FM(171,99,88) FM(172,100,89) FM(173,101,90) FM(174,102,91) FM(175,103,92) \
    FM(176,96,86) FM(177,97,87) FM(178,98,88) FM(179,99,89) FM(180,100,90) FM(181,101,91) FM(182,102,92) FM(183,103,93) \
    FM(184,96,87) FM(185,97,88) FM(186,98,89) FM(187,99,90) FM(188,100,91) FM(189,101,92) FM(190,102,93) FM(191,103,94) \
    FM(192,96,88) FM(193,97,89) FM(194,98,90) FM(195,99,91) FM(196,100,92) FM(197,101,93) FM(198,102,94) FM(199,103,95) \
    ::: PIPE_CLOB)

// slot D: wv v104-119, f v120-127
#define FMA_D asm volatile( \
    FM(128,120,104) FM(129,121,105) FM(130,122,106) FM(131,123,107) FM(132,124,108) FM(133,125,109) FM(134,126,110) FM(135,127,111) \
    FM(136,120,105) FM(137,121,106) FM(138,122,107) FM(139,123,108) FM(140,124,109) FM(141,125,110) FM(142,126,111) FM(143,127,112) \
    FM(144,120,106) FM(145,121,107) FM(146,122,108) FM(147,123,109) FM(148,124,110) FM(149,125,111) FM(150,126,112) FM(151,127,113) \
    FM(152,120,107) FM(153,121,108) FM(154,122,109) FM(155,123,110) FM(156,124,111) FM(157,125,112) FM(158,126,113) FM(159,127,114) \
    FM(160,120,108) FM(161,121,109) FM(162,122,110) FM(163,123,111) FM(164,124,112) FM(165,125,113) FM(166,126,114) FM(167,127,115) \
    FM(168,120,109) FM(169,121,110) FM(170,122,111) FM(171,123,112) FM(172,124,113) FM(173,125,114) FM(174,126,115) FM(175,127,116) \
    FM(176,120,110) FM(177,121,111) FM(178,122,112) FM(179,123,113) FM(180,124,114) FM(181,125,115) FM(182,126,116) FM(183,127,117) \
    FM(184,120,111) FM(185,121,112) FM(186,122,113) FM(187,123,114) FM(188,124,115) FM(189,125,116) FM(190,126,117) FM(191,127,118) \
    FM(192,120,112) FM(193,121,113) FM(194,122,114) FM(195,123,115) FM(196,124,116) FM(197,125,117) FM(198,126,118) FM(199,127,119) \
    ::: PIPE_CLOB)

// 6 loads per slot: window 4 chunks + first 2 chunks. q1/qf reuse offset:16.
#define ISSUE(W0,W4,W8,W12,F0,F4)                                        \
    asm volatile(                                                        \
        "global_load_dwordx4 v[" W0 "], %0, off\n\t"                     \
        "global_load_dwordx4 v[" W4 "], %1, off\n\t"                     \
        "global_load_dwordx4 v[" W8 "], %1, off offset:16\n\t"           \
        "global_load_dwordx4 v[" W12 "], %2, off\n\t"                    \
        "global_load_dwordx4 v[" F0 "], %3, off\n\t"                     \
        "global_load_dwordx4 v[" F4 "], %3, off offset:16"               \
        :: "v"(q0), "v"(q1), "v"(q3), "v"(qf) : PIPE_CLOB)

#define ISSUE_A ISSUE("32:35","36:39","40:43","44:47","48:51","52:55")
#define ISSUE_B ISSUE("56:59","60:63","64:67","68:71","72:75","76:79")
#define ISSUE_C ISSUE("80:83","84:87","88:91","92:95","96:99","100:103")
#define ISSUE_D ISSUE("104:107","108:111","112:115","116:119","120:123","124:127")

#define WAITVM(N) \
    asm volatile("s_waitcnt vmcnt(" #N ")" ::: "memory"); \
    __builtin_amdgcn_sched_barrier(0);

#define ADV  { q0 += s0; q1 += s1; q3 += s3; qf += CHB; }

__global__ __launch_bounds__(128, 2)
void corr_kernel(const float* __restrict__ first,
                 const float* __restrict__ second,
                 float* __restrict__ out)
{
    const int t  = threadIdx.x;
    const int lx = t & 7;        // 8 px each
    const int ry = t >> 3;       // 0..15 rows (2 waves x 8)
    const int x0 = blockIdx.x * TX;
    const int y0 = blockIdx.y * TY;
    const int bz = blockIdx.z;   // b*9 + (dy+4)
    const int b  = bz / 9;
    const int dyi = bz - 9 * b;  // 0..8
    const int dy  = dyi - 4;

    const int X = x0 + 8 * lx;   // this thread's first output x (mult of 8)
    const int y = y0 + ry;
    const int ys = y + dy;       // source row in second

    const float* fptr  = first  + (size_t)b * CHW_ + (size_t)y * W_ + X;
    const float* wbase = second + (size_t)b * CHW_ + (size_t)ys * W_ + (X - 4);

    const bool rowv = (ys >= 0) && (ys < H_);
    const bool v0 = rowv && (X >= 4);        // chunk [X-4, X)
    const bool v1 = rowv;                    // chunks [X, X+8) via q1+offset
    const bool v3 = rowv && (X <= 180);      // chunk [X+8, X+12)

    const uint64_t zp = (uint64_t)(uintptr_t)ZPAGE;
    uint64_t q0 = v0 ? (uint64_t)(uintptr_t)(wbase)      : zp;
    uint64_t q1 = v1 ? (uint64_t)(uintptr_t)(wbase + 4)  : zp;
    uint64_t q3 = v3 ? (uint64_t)(uintptr_t)(wbase + 12) : zp;
    uint64_t qf = (uint64_t)(uintptr_t)fptr;
    const uint64_t s0 = v0 ? CHB : 0;
    const uint64_t s1 = v1 ? CHB : 0;
    const uint64_t s3 = v3 ? CHB : 0;

    // zero acc block v128-v199
    asm volatile(
        ZM(128) ZM(129) ZM(130) ZM(131) ZM(132) ZM(133) ZM(134) ZM(135)
        ZM(136) ZM(137) ZM(138) ZM(139) ZM(140) ZM(141) ZM(142) ZM(143)
        ZM(144) ZM(145) ZM(146) ZM(147) ZM(148) ZM(149) ZM(150) ZM(151)
        ZM(152) ZM(153) ZM(154) ZM(155) ZM(156) ZM(157) ZM(158) ZM(159)
        ZM(160) ZM(161) ZM(162) ZM(163) ZM(164) ZM(165) ZM(166) ZM(167)
        ZM(168) ZM(169) ZM(170) ZM(171) ZM(172) ZM(173) ZM(174) ZM(175)
        ZM(176) ZM(177) ZM(178) ZM(179) ZM(180) ZM(181) ZM(182) ZM(183)
        ZM(184) ZM(185) ZM(186) ZM(187) ZM(188) ZM(189) ZM(190) ZM(191)
        ZM(192) ZM(193) ZM(194) ZM(195) ZM(196) ZM(197) ZM(198) ZM(199)
        ::: PIPE_CLOB);

    // prologue: channels 0..3 -> 24 loads in flight
    ISSUE_A; ADV
    ISSUE_B; ADV
    ISSUE_C; ADV
    ISSUE_D; ADV

    // steady: consume ch c (vmcnt(18): 3 newer slots x 6 loads stay in
    // flight), FMA, refill with ch c+4.
    #pragma unroll 1
    for (int it = 0; it < 31; ++it) {
        WAITVM(18) FMA_A; ISSUE_A; ADV
        WAITVM(18) FMA_B; ISSUE_B; ADV
        WAITVM(18) FMA_C; ISSUE_C; ADV
        WAITVM(18) FMA_D; ISSUE_D; ADV
    }
    // tail: channels 124..127, drain 18/12/6/0
    WAITVM(18) FMA_A;
    WAITVM(12) FMA_B;
    WAITVM(6)  FMA_C;
    WAITVM(0)  FMA_D;

    // read out acc v128-199 (sources clobbered so outputs get fresh regs)
    float rr[72];
#define RD18(base, o0) \
    asm volatile( \
        "v_mov_b32 %0, v" #base "\n\t"        "v_mov_b32 %1, v1" /*dummy*/ \
        : "=v"(rr[o0]) :: "v" #base);
    // (expanded explicitly below instead of a fragile macro)
    asm volatile(
        "v_mov_b32 %0, v128\n\t"  "v_mov_b32 %1, v129\n\t"
        "v_mov_b32 %2, v130\n\t"  "v_mov_b32 %3, v131\n\t"
        "v_mov_b32 %4, v132\n\t"  "v_mov_b32 %5, v133\n\t"
        "v_mov_b32 %6, v134\n\t"  "v_mov_b32 %7, v135\n\t"
        "v_mov_b32 %8, v136\n\t"  "v_mov_b32 %9, v137\n\t"
        "v_mov_b32 %10, v138\n\t" "v_mov_b32 %11, v139\n\t"
        "v_mov_b32 %12, v140\n\t" "v_mov_b32 %13, v141\n\t"
        "v_mov_b32 %14, v142\n\t" "v_mov_b32 %15, v143\n\t"
        "v_mov_b32 %16, v144\n\t" "v_mov_b32 %17, v145"
        : "=v"(rr[0]), "=v"(rr[1]), "=v"(rr[2]), "=v"(rr[3]),
          "=v"(rr[4]), "=v"(rr[5]), "=v"(rr[6]), "=v"(rr[7]),
          "=v"(rr[8]), "=v"(rr[9]), "=v"(rr[10]), "=v"(rr[11]),
          "=v"(rr[12]), "=v"(rr[13]), "=v"(rr[14]), "=v"(rr[15]),
          "=v"(rr[16]), "=v"(rr[17])
        :: "v128","v129","v130","v131","v132","v133","v134","v135","v136",
           "v137","v138","v139","v140","v141","v142","v143","v144","v145");
    asm volatile(
        "v_mov_b32 %0, v146\n\t"  "v_mov_b32 %1, v147\n\t"
        "v_mov_b32 %2, v148\n\t"  "v_mov_b32 %3, v149\n\t"
        "v_mov_b32 %4, v150\n\t"  "v_mov_b32 %5, v151\n\t"
        "v_mov_b32 %6, v152\n\t"  "v_mov_b32 %7, v153\n\t"
        "v_mov_b32 %8, v154\n\t"  "v_mov_b32 %9, v155\n\t"
        "v_mov_b32 %10, v156\n\t" "v_mov_b32 %11, v157\n\t"
        "v_mov_b32 %12, v158\n\t" "v_mov_b32 %13, v159\n\t"
        "v_mov_b32 %14, v160\n\t" "v_mov_b32 %15, v161\n\t"
        "v_mov_b32 %16, v162\n\t" "v_mov_b32 %17, v163"
        : "=v"(rr[18]), "=v"(rr[19]), "=v"(rr[20]), "=v"(rr[21]),
          "=v"(rr[22]), "=v"(rr[23]), "=v"(rr[24]), "=v"(rr[25]),
          "=v"(rr[26]), "=v"(rr[27]), "=v"(rr[28]), "=v"(rr[29]),
          "=v"(rr[30]), "=v"(rr[31]), "=v"(rr[32]), "=v"(rr[33]),
          "=v"(rr[34]), "=v"(rr[35])
        :: "v146","v147","v148","v149","v150","v151","v152","v153","v154",
           "v155","v156","v157","v158","v159","v160","v161","v162","v163");
    asm volatile(
        "v_mov_b32 %0, v164\n\t"  "v_mov_b32 %1, v165\n\t"
        "v_mov_b32 %2, v166\n\t"  "v_mov_b32 %3, v167\n\t"
        "v_mov_b32 %4, v168\n\t"  "v_mov_b32 %5, v169\n\t"
        "v_mov_b32 %6, v170\n\t"  "v_mov_b32 %7, v171\n\t"
        "v_mov_b32 %8, v172\n\t"  "v_mov_b32 %9, v173\n\t"
        "v_mov_b32 %10, v174\n\t" "v_mov_b32 %11, v175\n\t"
        "v_mov_b32 %12, v176\n\t" "v_mov_b32 %13, v177\n\t"
        "v_mov_b32 %14, v178\n\t" "v_mov_b32 %15, v179\n\t"
        "v_mov_b32 %16, v180\n\t" "v_mov_b32 %17, v181"
        : "=v"(rr[36]), "=v"(rr[37]), "=v"(rr[38]), "=v"(rr[39]),
          "=v"(rr[40]), "=v"(rr[41]), "=v"(rr[42]), "=v"(rr[43]),
          "=v"(rr[44]), "=v"(rr[45]), "=v"(rr[46]), "=v"(rr[47]),
          "=v"(rr[48]), "=v"(rr[49]), "=v"(rr[50]), "=v"(rr[51]),
          "=v"(rr[52]), "=v"(rr[53])
        :: "v164","v165","v166","v167","v168","v169","v170","v171","v172",
           "v173","v174","v175","v176","v177","v178","v179","v180","v181");
    asm volatile(
        "v_mov_b32 %0, v182\n\t"  "v_mov_b32 %1, v183\n\t"
        "v_mov_b32 %2, v184\n\t"  "v_mov_b32 %3, v185\n\t"
        "v_mov_b32 %4, v186\n\t"  "v_mov_b32 %5, v187\n\t"
        "v_mov_b32 %6, v188\n\t"  "v_mov_b32 %7, v189\n\t"
        "v_mov_b32 %8, v190\n\t"  "v_mov_b32 %9, v191\n\t"
        "v_mov_b32 %10, v192\n\t" "v_mov_b32 %11, v193\n\t"
        "v_mov_b32 %12, v194\n\t" "v_mov_b32 %13, v195\n\t"
        "v_mov_b32 %14, v196\n\t" "v_mov_b32 %15, v197\n\t"
        "v_mov_b32 %16, v198\n\t" "v_mov_b32 %17, v199"
        : "=v"(rr[54]), "=v"(rr[55]), "=v"(rr[56]), "=v"(rr[57]),
          "=v"(rr[58]), "=v"(rr[59]), "=v"(rr[60]), "=v"(rr[61]),
          "=v"(rr[62]), "=v"(rr[63]), "=v"(rr[64]), "=v"(rr[65]),
          "=v"(rr[66]), "=v"(rr[67]), "=v"(rr[68]), "=v"(rr[69]),
          "=v"(rr[70]), "=v"(rr[71])
        :: "v182","v183","v184","v185","v186","v187","v188","v189","v190",
           "v191","v192","v193","v194","v195","v196","v197","v198","v199");

    // epilogue: out[b, dyi*9 + dxi, y, X..X+7]
    const float scale = 1.0f / (float)C_;
    #pragma unroll
    for (int dxi = 0; dxi < 9; ++dxi) {
        const int d = dyi * 9 + dxi;
        float* op = out + ((size_t)b * 81 + d) * HW_ + (size_t)y * W_ + X;
        float4 r0, r1;
        r0.x = rr[8*dxi + 0] * scale; r0.y = rr[8*dxi + 1] * scale;
        r0.z = rr[8*dxi + 2] * scale; r0.w = rr[8*dxi + 3] * scale;
        r1.x = rr[8*dxi + 4] * scale; r1.y = rr[8*dxi + 5] * scale;
        r1.z = rr[8*dxi + 6] * scale; r1.w = rr[8*dxi + 7] * scale;
        *(float4*)(op)     = r0;
        *(float4*)(op + 4) = r1;
    }
}

extern "C" void kernel_launch(void* const* d_in, const int* in_sizes, int n_in,
                              void* d_out, int out_size, void* d_ws, size_t ws_size,
                              hipStream_t stream) {
    const float* first  = (const float*)d_in[0];
    const float* second = (const float*)d_in[1];
    float* out = (float*)d_out;

    dim3 grid(W_ / TX, H_ / TY, B_ * 9);   // 3 x 8 x 36 = 864 blocks
    dim3 block(128);
    corr_kernel<<<grid, block, 0, stream>>>(first, second, out);
}